// Round 2
// baseline (278.361 us; speedup 1.0000x reference)
//
#include <hip/hip_runtime.h>

// GraphConvolution: out[b,n,o] = sum_m adj[n,m] * (F[b,m,:] . W[o,:]) + b[o]
// B=8192, N=4, DIN=1024, DOUT=256.
//
// R4: drop d_ws entirely. The timed graph contains two 512-MiB workspace
// re-poison fills (~157 us of ~220 us); testing whether they are tied to
// workspace use. Consequence: no pre-converted bf16 W image -> load W fp32
// straight from L2 into VGPRs and convert with the same RTNE f2bf (bit-
// identical results). That in turn removes the last LDS use (A staging):
// A fragments are loaded fp32 per-lane directly from feat (L1/L2 absorbs the
// 4x intra-block reuse) -> ZERO barriers, zero LDS, fully asynchronous waves.
// A regs double-buffered one kb ahead (HBM latency); B loads issued at the
// top of each iteration (L2-resident, hides under cvt+MFMA).

#define DIN 1024
#define DOUT 256
#define BM 64
#define KI 16  // DIN / 64

typedef __bf16 bf16x8 __attribute__((ext_vector_type(8)));
typedef float f32x4 __attribute__((ext_vector_type(4)));
typedef unsigned short u16x8 __attribute__((ext_vector_type(8)));

__device__ __forceinline__ unsigned short f2bf(float f) {
  union { float f; unsigned int u; } v;
  v.f = f;
  unsigned int u = v.u;
  u += 0x7fffu + ((u >> 16) & 1u);   // round-to-nearest-even
  return (unsigned short)(u >> 16);
}

__device__ __forceinline__ bf16x8 pack8(f32x4 lo, f32x4 hi) {
  union { u16x8 u; bf16x8 b; } r;
#pragma unroll
  for (int m = 0; m < 4; ++m) {
    r.u[m] = f2bf(lo[m]);
    r.u[4 + m] = f2bf(hi[m]);
  }
  return r.b;
}

__global__ __launch_bounds__(256, 2) void gconv_kernel(
    const float* __restrict__ adj, const float* __restrict__ feat,
    const float* __restrict__ W, const float* __restrict__ bias,
    float* __restrict__ out) {
  const int tid = threadIdx.x;
  const int bM = blockIdx.x * BM;

  // wave coords: 1x4 wave grid, each wave owns 64 rows x 64 cols
  const int lane = tid & 63;
  const int wid = tid >> 6;
  const int wc = wid * 64;
  const int rl = lane & 15;
  const int q = lane >> 4;
  const int q8 = q * 8;

  // MFMA 16x16x32 A/B fragment: lane(rl,q) holds [row=rl][k=q*8..q*8+8]
  const float* ab = feat + (size_t)(bM + rl) * DIN + q8;
  const float* bb = W + (size_t)(wc + rl) * DIN + q8;

  f32x4 acc[4][4];
#pragma unroll
  for (int i = 0; i < 4; ++i)
#pragma unroll
    for (int j = 0; j < 4; ++j) acc[i][j] = f32x4{0.f, 0.f, 0.f, 0.f};

  // A fp32 double-buffer: 16 f32x4 (one full kb of A fragments)
  f32x4 a4[4][2][2];
#pragma unroll
  for (int i = 0; i < 4; ++i)
#pragma unroll
    for (int ks = 0; ks < 2; ++ks)
#pragma unroll
      for (int h = 0; h < 2; ++h)
        a4[i][ks][h] =
            *(const f32x4*)(ab + (size_t)i * 16 * DIN + ks * 32 + h * 4);

  for (int kb = 0; kb < KI; ++kb) {
    // B for this kb: issue all 16 loads first (L2-resident W)
    f32x4 b4[4][2][2];
#pragma unroll
    for (int j = 0; j < 4; ++j)
#pragma unroll
      for (int ks = 0; ks < 2; ++ks)
#pragma unroll
        for (int h = 0; h < 2; ++h)
          b4[j][ks][h] = *(const f32x4*)(bb + (size_t)j * 16 * DIN + kb * 64 +
                                         ks * 32 + h * 4);

    // convert current A regs to bf16 fragments (frees a4 for the prefetch)
    bf16x8 af[2][4];
#pragma unroll
    for (int ks = 0; ks < 2; ++ks)
#pragma unroll
      for (int i = 0; i < 4; ++i)
        af[ks][i] = pack8(a4[i][ks][0], a4[i][ks][1]);

    // prefetch next kb of A (HBM; latency covered by this iter's cvt+MFMA)
    if (kb + 1 < KI) {
#pragma unroll
      for (int i = 0; i < 4; ++i)
#pragma unroll
        for (int ks = 0; ks < 2; ++ks)
#pragma unroll
          for (int h = 0; h < 2; ++h)
            a4[i][ks][h] = *(const f32x4*)(ab + (size_t)i * 16 * DIN +
                                           (kb + 1) * 64 + ks * 32 + h * 4);
    }

    bf16x8 bfr[2][4];
#pragma unroll
    for (int ks = 0; ks < 2; ++ks)
#pragma unroll
      for (int j = 0; j < 4; ++j)
        bfr[ks][j] = pack8(b4[j][ks][0], b4[j][ks][1]);

#pragma unroll
    for (int ks = 0; ks < 2; ++ks)
#pragma unroll
      for (int i = 0; i < 4; ++i)
#pragma unroll
        for (int j = 0; j < 4; ++j)
          acc[i][j] = __builtin_amdgcn_mfma_f32_16x16x32_bf16(
              af[ks][i], bfr[ks][j], acc[i][j], 0, 0, 0);
  }

  // epilogue: adj 4x4 mix (regs = rows 4q..4q+3 of one batch) + bias
  float am[16];
#pragma unroll
  for (int i = 0; i < 16; ++i) am[i] = adj[i];  // uniform -> scalar loads

  float bv[4];
#pragma unroll
  for (int j = 0; j < 4; ++j) bv[j] = bias[wc + j * 16 + rl];

#pragma unroll
  for (int i = 0; i < 4; ++i) {
    const size_t rowbase = (size_t)(bM + i * 16 + q * 4);
#pragma unroll
    for (int j = 0; j < 4; ++j) {
      const int col = wc + j * 16 + rl;
      float* op = out + rowbase * DOUT + col;
      f32x4 g = acc[i][j];
#pragma unroll
      for (int n = 0; n < 4; ++n) {
        op[(size_t)n * DOUT] = am[n * 4 + 0] * g[0] + am[n * 4 + 1] * g[1] +
                               am[n * 4 + 2] * g[2] + am[n * 4 + 3] * g[3] +
                               bv[j];
      }
    }
  }
}

extern "C" void kernel_launch(void* const* d_in, const int* in_sizes, int n_in,
                              void* d_out, int out_size, void* d_ws,
                              size_t ws_size, hipStream_t stream) {
  const float* adj = (const float*)d_in[0];
  const float* feat = (const float*)d_in[1];
  const float* W = (const float*)d_in[2];
  const float* bias = (const float*)d_in[3];
  float* out = (float*)d_out;
  (void)d_ws;
  (void)ws_size;

  gconv_kernel<<<8192 * 4 / BM, 256, 0, stream>>>(adj, feat, W, bias, out);
}

// Round 4
// 239.233 us; speedup vs baseline: 1.1636x; 1.1636x over previous
//
#include <hip/hip_runtime.h>

// GraphConvolution: out[b,n,o] = sum_m adj[n,m] * (F[b,m,:] . W[o,:]) + b[o]
// B=8192, N=4, DIN=1024, DOUT=256.
//
// R5 (resubmit; prior round hit GPUAcquisitionTimeout, never measured):
// the two 512-MiB workspace poison fills (~157 us) are UNCONDITIONAL
// (R4 showed them present even with d_ws unused), so using ws is free ->
// keep the bf16 W image. gconv itself was grid-capped: 512 blocks =
// 2 blocks/CU = 8 waves/CU in every prior version (launch_bounds couldn't
// help). BM 64->32: grid 1024 -> 4 blocks/CU = 16 waves/CU, acc 2x4
// (32 VGPR) fits __launch_bounds__(256,4). Keep R3's verified scheme:
// A fp32 coalesced -> regs -> bf16 -> LDS (double-buffered, raw s_barrier
// waiting lgkmcnt only, vmcnt never drained), B read bf16x8 straight from
// the L2-resident W image, adj 4x4 mix + bias in the epilogue.

#define DIN 1024
#define DOUT 256
#define BM 32
#define KI 16                      // DIN / 64
#define LDB 72                     // sA padded row stride in bf16
#define A_HALFS (BM * LDB)         // 2304 ushorts per A buffer

typedef __bf16 bf16x8 __attribute__((ext_vector_type(8)));
typedef float f32x4 __attribute__((ext_vector_type(4)));
typedef unsigned short u16x8 __attribute__((ext_vector_type(8)));

__device__ __forceinline__ unsigned short f2bf(float f) {
  union { float f; unsigned int u; } v;
  v.f = f;
  unsigned int u = v.u;
  u += 0x7fffu + ((u >> 16) & 1u);   // round-to-nearest-even
  return (unsigned short)(u >> 16);
}

// Pre-kernel: W [256x1024] fp32 -> bf16, same layout (row-major [col][k]).
__global__ __launch_bounds__(256) void wprep_kernel(
    const float* __restrict__ W, unsigned short* __restrict__ ws) {
  const int t = blockIdx.x * 256 + threadIdx.x;  // 32768 threads x 8 elems
  const f32x4* src = (const f32x4*)(W + (size_t)t * 8);
  f32x4 a = src[0], b = src[1];
  u16x8 pk;
#pragma unroll
  for (int m = 0; m < 4; ++m) {
    pk[m] = f2bf(a[m]);
    pk[4 + m] = f2bf(b[m]);
  }
  *(u16x8*)(ws + (size_t)t * 8) = pk;
}

__global__ __launch_bounds__(256, 4) void gconv_kernel(
    const float* __restrict__ adj, const float* __restrict__ feat,
    const unsigned short* __restrict__ wbf, const float* __restrict__ bias,
    float* __restrict__ out) {
  __shared__ __align__(16) unsigned short sA[2][A_HALFS];  // 2 x 4.5 KB

  const int tid = threadIdx.x;
  const int bM = blockIdx.x * BM;

  // A staging: thread owns one 8-float chunk of one row (32 rows x 8 chunks)
  const int row0 = tid >> 3;          // 0..31
  const int kc8 = (tid & 7) * 8;      // float offset within K-block
  const float* aptr = feat + (size_t)(bM + row0) * DIN + kc8;
  unsigned short* sw0 = &sA[0][row0 * LDB + kc8];
  unsigned short* sw1 = &sA[1][row0 * LDB + kc8];

  // wave coords: 1x4 wave grid, each wave owns 32 rows x 64 cols
  const int lane = tid & 63;
  const int wid = tid >> 6;
  const int wc = wid * 64;
  const int rl = lane & 15;
  const int q = lane >> 4;
  const int q8 = q * 8;

  // per-lane B base: col = wc + j*16 + rl, k = kb*64 + ks*32 + q*8
  const unsigned short* bp0 = wbf + (size_t)(wc + rl) * DIN + q8;

  f32x4 acc[2][4];
#pragma unroll
  for (int i = 0; i < 2; ++i)
#pragma unroll
    for (int j = 0; j < 4; ++j) acc[i][j] = f32x4{0.f, 0.f, 0.f, 0.f};

  // prologue: kb=0 A chunk -> regs -> bf16 -> sA[0]
  f32x4 pa0 = *(const f32x4*)aptr;
  f32x4 pa1 = *(const f32x4*)(aptr + 4);
  {
    u16x8 pk;
#pragma unroll
    for (int m = 0; m < 4; ++m) {
      pk[m] = f2bf(pa0[m]);
      pk[4 + m] = f2bf(pa1[m]);
    }
    *(u16x8*)sw0 = pk;
  }
  // prefetch A for kb=1 (stays in flight across the raw barrier)
  pa0 = *(const f32x4*)(aptr + 64);
  pa1 = *(const f32x4*)(aptr + 68);

  for (int kb = 0; kb < KI; ++kb) {
    // B fragments for this kb: direct L2 -> VGPR, issued BEFORE the barrier
    // so their latency hides under the barrier wait (vmcnt not drained).
    bf16x8 bfr[2][4];
#pragma unroll
    for (int ks = 0; ks < 2; ++ks)
#pragma unroll
      for (int j = 0; j < 4; ++j)
        bfr[ks][j] =
            *(const bf16x8*)(bp0 + (size_t)j * 16 * DIN + kb * 64 + ks * 32);

    // raw barrier: wait only LDS ops (sA writes/reads), never vmcnt.
    __builtin_amdgcn_sched_barrier(0);
    asm volatile("s_waitcnt lgkmcnt(0)" ::: "memory");
    __builtin_amdgcn_s_barrier();
    __builtin_amdgcn_sched_barrier(0);

    const unsigned short* sa = (kb & 1) ? &sA[1][0] : &sA[0][0];
#pragma unroll
    for (int ks = 0; ks < 2; ++ks) {
      const int ko = ks * 32 + q8;
      bf16x8 af[2];
#pragma unroll
      for (int i = 0; i < 2; ++i)
        af[i] = *(const bf16x8*)(sa + (i * 16 + rl) * LDB + ko);
#pragma unroll
      for (int i = 0; i < 2; ++i)
#pragma unroll
        for (int j = 0; j < 4; ++j)
          acc[i][j] = __builtin_amdgcn_mfma_f32_16x16x32_bf16(
              af[i], bfr[ks][j], acc[i][j], 0, 0, 0);
    }

    // stage next A tile into the other buffer; visibility handled by the
    // next iteration's lgkmcnt(0)+barrier (R3-verified scheme).
    if (kb + 1 < KI) {
      u16x8 pk;
#pragma unroll
      for (int m = 0; m < 4; ++m) {
        pk[m] = f2bf(pa0[m]);
        pk[4 + m] = f2bf(pa1[m]);
      }
      unsigned short* sw = ((kb + 1) & 1) ? sw1 : sw0;
      *(u16x8*)sw = pk;
      if (kb + 2 < KI) {
        const float* a0 = aptr + (size_t)(kb + 2) * 64;
        pa0 = *(const f32x4*)a0;
        pa1 = *(const f32x4*)(a0 + 4);
      }
    }
  }

  // epilogue: adj 4x4 mix (regs = rows 4q..4q+3 of one batch) + bias
  float am[16];
#pragma unroll
  for (int i = 0; i < 16; ++i) am[i] = adj[i];  // uniform -> scalar loads

  float bv[4];
#pragma unroll
  for (int j = 0; j < 4; ++j) bv[j] = bias[wc + j * 16 + rl];

#pragma unroll
  for (int i = 0; i < 2; ++i) {
    const size_t rowbase = (size_t)(bM + i * 16 + q * 4);
#pragma unroll
    for (int j = 0; j < 4; ++j) {
      const int col = wc + j * 16 + rl;
      float* op = out + rowbase * DOUT + col;
      f32x4 g = acc[i][j];
#pragma unroll
      for (int n = 0; n < 4; ++n) {
        op[(size_t)n * DOUT] = am[n * 4 + 0] * g[0] + am[n * 4 + 1] * g[1] +
                               am[n * 4 + 2] * g[2] + am[n * 4 + 3] * g[3] +
                               bv[j];
      }
    }
  }
}

extern "C" void kernel_launch(void* const* d_in, const int* in_sizes, int n_in,
                              void* d_out, int out_size, void* d_ws,
                              size_t ws_size, hipStream_t stream) {
  const float* adj = (const float*)d_in[0];
  const float* feat = (const float*)d_in[1];
  const float* W = (const float*)d_in[2];
  const float* bias = (const float*)d_in[3];
  float* out = (float*)d_out;
  unsigned short* ws = (unsigned short*)d_ws;  // 256*1024*2 B = 512 KB

  wprep_kernel<<<128, 256, 0, stream>>>(W, ws);
  gconv_kernel<<<8192 * 4 / BM, 256, 0, stream>>>(adj, feat, ws, bias, out);
}

// Round 5
// 223.269 us; speedup vs baseline: 1.2468x; 1.0715x over previous
//
#include <hip/hip_runtime.h>

// GraphConvolution: out[b,n,o] = sum_m adj[n,m] * (F[b,m,:] . W[o,:]) + b[o]
// B=8192, N=4, DIN=1024, DOUT=256.
//
// R6: R5 showed gconv latency-bound at 91us with everything idle. Cause:
// B-fragment loads scatter 16 B/lane across 16 cache lines 2 KB apart
// (~256 VMEM transactions per kb per wave saturating the TA pipe). Fix:
// wprep now emits the W image in MFMA-FRAGMENT ORDER -- 1-KB chunks where
// lane l's 16 bytes are W[g*64+j*16+(l&15)][kb*64+ks*32+(l>>4)*8..+8] --
// so every B load in gconv is base + lane*16: ONE coalesced wave
// transaction. 16x fewer VMEM transactions, bit-identical values.
// A path unchanged from R5 (fp32 coalesced -> f2bf -> LDS dbuf, raw
// s_barrier waiting lgkmcnt only; BM=32, grid 1024 = 4 blocks/CU).

#define DIN 1024
#define DOUT 256
#define BM 32
#define KI 16                      // DIN / 64
#define LDB 72                     // sA padded row stride in bf16
#define A_HALFS (BM * LDB)         // 2304 ushorts per A buffer

typedef __bf16 bf16x8 __attribute__((ext_vector_type(8)));
typedef float f32x4 __attribute__((ext_vector_type(4)));
typedef unsigned short u16x8 __attribute__((ext_vector_type(8)));

__device__ __forceinline__ unsigned short f2bf(float f) {
  union { float f; unsigned int u; } v;
  v.f = f;
  unsigned int u = v.u;
  u += 0x7fffu + ((u >> 16) & 1u);   // round-to-nearest-even
  return (unsigned short)(u >> 16);
}

// Pre-kernel: W [256x1024] fp32 -> bf16 in MFMA-fragment order.
// Chunk c = ((g*16 + kb)*2 + ks)*4 + j  (512 chunks x 1 KB = 512 KB);
// within a chunk, lane l holds W[g*64+j*16+(l&15)][kb*64+ks*32+(l>>4)*8..+8].
__global__ __launch_bounds__(256) void wprep_kernel(
    const float* __restrict__ W, unsigned short* __restrict__ ws) {
  const int t = blockIdx.x * 256 + threadIdx.x;  // 32768 threads, one bf16x8 each
  const int lane = t & 63;
  const int j = (t >> 6) & 3;
  const int ks = (t >> 8) & 1;
  const int kb = (t >> 9) & 15;
  const int g = (t >> 13) & 3;
  const int col = g * 64 + j * 16 + (lane & 15);
  const int k0 = kb * 64 + ks * 32 + (lane >> 4) * 8;
  const f32x4* src = (const f32x4*)(W + (size_t)col * DIN + k0);
  f32x4 a = src[0], b = src[1];
  u16x8 pk;
#pragma unroll
  for (int m = 0; m < 4; ++m) {
    pk[m] = f2bf(a[m]);
    pk[4 + m] = f2bf(b[m]);
  }
  *(u16x8*)(ws + (size_t)t * 8) = pk;
}

__global__ __launch_bounds__(256, 4) void gconv_kernel(
    const float* __restrict__ adj, const float* __restrict__ feat,
    const unsigned short* __restrict__ wbf, const float* __restrict__ bias,
    float* __restrict__ out) {
  __shared__ __align__(16) unsigned short sA[2][A_HALFS];  // 2 x 4.5 KB

  const int tid = threadIdx.x;
  const int bM = blockIdx.x * BM;

  // A staging: thread owns one 8-float chunk of one row (32 rows x 8 chunks)
  const int row0 = tid >> 3;          // 0..31
  const int kc8 = (tid & 7) * 8;      // float offset within K-block
  const float* aptr = feat + (size_t)(bM + row0) * DIN + kc8;
  unsigned short* sw0 = &sA[0][row0 * LDB + kc8];
  unsigned short* sw1 = &sA[1][row0 * LDB + kc8];

  // wave coords: 1x4 wave grid, each wave owns 32 rows x 64 cols
  const int lane = tid & 63;
  const int wid = tid >> 6;
  const int wc = wid * 64;
  const int rl = lane & 15;
  const int q = lane >> 4;
  const int q8 = q * 8;

  // fragment-ordered B: wave 'wid' owns chunks [wid*128 .. wid*128+127];
  // per (kb,ks,j) chunk offset ((kb*2+ks)*4+j)*512 halfs, lane-contiguous.
  const unsigned short* bp = wbf + (size_t)wid * 128 * 512 + lane * 8;

  f32x4 acc[2][4];
#pragma unroll
  for (int i = 0; i < 2; ++i)
#pragma unroll
    for (int j = 0; j < 4; ++j) acc[i][j] = f32x4{0.f, 0.f, 0.f, 0.f};

  // prologue: kb=0 A chunk -> regs -> bf16 -> sA[0]
  f32x4 pa0 = *(const f32x4*)aptr;
  f32x4 pa1 = *(const f32x4*)(aptr + 4);
  {
    u16x8 pk;
#pragma unroll
    for (int m = 0; m < 4; ++m) {
      pk[m] = f2bf(pa0[m]);
      pk[4 + m] = f2bf(pa1[m]);
    }
    *(u16x8*)sw0 = pk;
  }
  // prefetch A for kb=1 (stays in flight across the raw barrier)
  pa0 = *(const f32x4*)(aptr + 64);
  pa1 = *(const f32x4*)(aptr + 68);

  for (int kb = 0; kb < KI; ++kb) {
    // B fragments: one coalesced 1-KB wave load each, issued BEFORE the
    // barrier so their L2 latency hides under the barrier wait.
    bf16x8 bfr[2][4];
#pragma unroll
    for (int ks = 0; ks < 2; ++ks)
#pragma unroll
      for (int j = 0; j < 4; ++j)
        bfr[ks][j] = *(const bf16x8*)(bp + ((kb * 2 + ks) * 4 + j) * 512);

    // raw barrier: wait only LDS ops (sA writes/reads), never vmcnt.
    __builtin_amdgcn_sched_barrier(0);
    asm volatile("s_waitcnt lgkmcnt(0)" ::: "memory");
    __builtin_amdgcn_s_barrier();
    __builtin_amdgcn_sched_barrier(0);

    const unsigned short* sa = (kb & 1) ? &sA[1][0] : &sA[0][0];
#pragma unroll
    for (int ks = 0; ks < 2; ++ks) {
      const int ko = ks * 32 + q8;
      bf16x8 af[2];
#pragma unroll
      for (int i = 0; i < 2; ++i)
        af[i] = *(const bf16x8*)(sa + (i * 16 + rl) * LDB + ko);
#pragma unroll
      for (int i = 0; i < 2; ++i)
#pragma unroll
        for (int j = 0; j < 4; ++j)
          acc[i][j] = __builtin_amdgcn_mfma_f32_16x16x32_bf16(
              af[i], bfr[ks][j], acc[i][j], 0, 0, 0);
    }

    // stage next A tile into the other buffer; visibility handled by the
    // next iteration's lgkmcnt(0)+barrier (R3/R5-verified scheme).
    if (kb + 1 < KI) {
      u16x8 pk;
#pragma unroll
      for (int m = 0; m < 4; ++m) {
        pk[m] = f2bf(pa0[m]);
        pk[4 + m] = f2bf(pa1[m]);
      }
      unsigned short* sw = ((kb + 1) & 1) ? sw1 : sw0;
      *(u16x8*)sw = pk;
      if (kb + 2 < KI) {
        const float* a0 = aptr + (size_t)(kb + 2) * 64;
        pa0 = *(const f32x4*)a0;
        pa1 = *(const f32x4*)(a0 + 4);
      }
    }
  }

  // epilogue: adj 4x4 mix (regs = rows 4q..4q+3 of one batch) + bias
  float am[16];
#pragma unroll
  for (int i = 0; i < 16; ++i) am[i] = adj[i];  // uniform -> scalar loads

  float bv[4];
#pragma unroll
  for (int j = 0; j < 4; ++j) bv[j] = bias[wc + j * 16 + rl];

#pragma unroll
  for (int i = 0; i < 2; ++i) {
    const size_t rowbase = (size_t)(bM + i * 16 + q * 4);
#pragma unroll
    for (int j = 0; j < 4; ++j) {
      const int col = wc + j * 16 + rl;
      float* op = out + rowbase * DOUT + col;
      f32x4 g = acc[i][j];
#pragma unroll
      for (int n = 0; n < 4; ++n) {
        op[(size_t)n * DOUT] = am[n * 4 + 0] * g[0] + am[n * 4 + 1] * g[1] +
                               am[n * 4 + 2] * g[2] + am[n * 4 + 3] * g[3] +
                               bv[j];
      }
    }
  }
}

extern "C" void kernel_launch(void* const* d_in, const int* in_sizes, int n_in,
                              void* d_out, int out_size, void* d_ws,
                              size_t ws_size, hipStream_t stream) {
  const float* adj = (const float*)d_in[0];
  const float* feat = (const float*)d_in[1];
  const float* W = (const float*)d_in[2];
  const float* bias = (const float*)d_in[3];
  float* out = (float*)d_out;
  unsigned short* ws = (unsigned short*)d_ws;  // 512 KB fragment-ordered image

  wprep_kernel<<<128, 256, 0, stream>>>(W, ws);
  gconv_kernel<<<8192 * 4 / BM, 256, 0, stream>>>(adj, feat, ws, bias, out);
}